// Round 15
// baseline (376.220 us; speedup 1.0000x reference)
//
#include <hip/hip_runtime.h>
#include <hip/hip_bf16.h>

typedef __attribute__((ext_vector_type(8))) short short8;
typedef __attribute__((ext_vector_type(4))) float floatx4;
typedef __attribute__((ext_vector_type(16))) float floatx16;

__device__ __forceinline__ unsigned short f2bf(float x) {
  __hip_bfloat16 h = __float2bfloat16(x);
  return __builtin_bit_cast(unsigned short, h);
}
__device__ __forceinline__ float bf2f(unsigned short u) {
  return __builtin_bit_cast(float, (unsigned int)u << 16);
}

// ---------------------------------------------------------------------
// X (fp32) -> bf16 copy
// ---------------------------------------------------------------------
__global__ __launch_bounds__(256) void cvt_x_kernel(
    const float* __restrict__ X, unsigned short* __restrict__ Xbf, int n) {
  int i = blockIdx.x * 256 + threadIdx.x;
  if (i < n) Xbf[i] = f2bf(X[i]);
}

// ---------------------------------------------------------------------
// Pack extended weights [W | root] into MFMA B-fragment order:
// Bpk[(((kc*4)+wv)*64 + lane)*8 + j] = Wext[wv*16 + (lane&15)]
//                                          [kc*32 + ((lane>>4)&3)*8 + j]
// K2=0 packs just a 64x64 matrix from `root`.
// ---------------------------------------------------------------------
__global__ __launch_bounds__(256) void pack_b_kernel(
    const float* __restrict__ W, const float* __restrict__ root,
    unsigned short* __restrict__ Bpk, int K2) {
  int R = (K2 + 1) * 64;
  int total = 64 * R;
  int i = blockIdx.x * 256 + threadIdx.x;
  if (i >= total) return;
  int j = i & 7;
  int lane = (i >> 3) & 63;
  int rest = i >> 9;            // kc*4 + wv
  int wv = rest & 3, kc = rest >> 2;
  int o = wv * 16 + (lane & 15);
  int r = kc * 32 + ((lane >> 4) & 3) * 8 + j;
  int k = r >> 6, d = r & 63;
  float v = (k < K2) ? W[(k << 12) + (d << 6) + o] : root[(d << 6) + o];
  Bpk[i] = f2bf(v);
}

// ---------------------------------------------------------------------
// CSR build: histogram -> scan -> cursor scatter (emits packed edge recs)
// ---------------------------------------------------------------------
__global__ __launch_bounds__(256) void zero_int_kernel(int* __restrict__ p, int n) {
  int i = blockIdx.x * 256 + threadIdx.x;
  if (i < n) p[i] = 0;
}

__global__ __launch_bounds__(256) void hist_kernel(
    const int* __restrict__ dst, int* __restrict__ deg, int nE) {
  int e = blockIdx.x * 256 + threadIdx.x;
  if (e < nE) atomicAdd(&deg[dst[e]], 1);
}

__global__ __launch_bounds__(256) void blocksum_kernel(
    const int* __restrict__ deg, int* __restrict__ partial, int N) {
  __shared__ int s[256];
  int t = threadIdx.x, i = blockIdx.x * 256 + t;
  s[t] = (i < N) ? deg[i] : 0;
  __syncthreads();
  for (int off = 128; off > 0; off >>= 1) {
    if (t < off) s[t] += s[t + off];
    __syncthreads();
  }
  if (t == 0) partial[blockIdx.x] = s[0];
}

__global__ __launch_bounds__(256) void scanpartials_kernel(
    int* __restrict__ partial, int nb) {
  __shared__ int s[256];
  int t = threadIdx.x;
  int v = (t < nb) ? partial[t] : 0;
  s[t] = v;
  __syncthreads();
  for (int off = 1; off < 256; off <<= 1) {
    int x = (t >= off) ? s[t - off] : 0;
    __syncthreads();
    s[t] += x;
    __syncthreads();
  }
  if (t < nb) partial[t] = s[t] - v;
}

__global__ __launch_bounds__(256) void blockscan_kernel(
    const int* __restrict__ deg, const int* __restrict__ partial,
    int* __restrict__ row_start, int* __restrict__ cursor, int N, int nE) {
  __shared__ int s[256];
  int t = threadIdx.x, i = blockIdx.x * 256 + t;
  int v = (i < N) ? deg[i] : 0;
  s[t] = v;
  __syncthreads();
  for (int off = 1; off < 256; off <<= 1) {
    int x = (t >= off) ? s[t - off] : 0;
    __syncthreads();
    s[t] += x;
    __syncthreads();
  }
  if (i < N) {
    int excl = s[t] - v + partial[blockIdx.x];
    row_start[i] = excl;
    cursor[i] = excl;
  }
  if (i == 0) row_start[N] = nE;
}

// Record: x=f0, y=f1, z=bit(l0|l1<<8), w=bit(src*64). One per edge per K.
__global__ __launch_bounds__(256) void scatter_rec_kernel(
    const int* __restrict__ dst, const int* __restrict__ src,
    const float* __restrict__ attr, int* __restrict__ cursor,
    float4* __restrict__ rec3, float4* __restrict__ rec5, int nE) {
  int e = blockIdx.x * 256 + threadIdx.x;
  if (e >= nE) return;
  int pos = atomicAdd(&cursor[dst[e]], 1);
  float2 a = *(const float2*)&attr[2 * e];
  int off = src[e] * 64;
  {
    float u = a.x * 2.f, v = a.y * 2.f;
    int l0 = min((int)u, 1), l1 = min((int)v, 1);
    rec3[pos] = make_float4(u - (float)l0, v - (float)l1,
                            __builtin_bit_cast(float, l0 | (l1 << 8)),
                            __builtin_bit_cast(float, off));
  }
  {
    float u = a.x * 4.f, v = a.y * 4.f;
    int l0 = min((int)u, 3), l1 = min((int)v, 3);
    rec5[pos] = make_float4(u - (float)l0, v - (float)l1,
                            __builtin_bit_cast(float, l0 | (l1 << 8)),
                            __builtin_bit_cast(float, off));
  }
}

// ---------------------------------------------------------------------
// FUSED spline layer: block = 4 waves = 8 dst nodes (2 nodes/wave).
// Phase 1 (per wave): MFMA bucket-aggregate (32x32x16) from packed edge
//   records; scaled Z + root row -> LDS (8 rows, 26.75 KB @ K=5 ->
//   6 blocks/CU = 24 waves, vs R13's 3 blocks/12 waves).
// Phase 2: out[8 x 64] = ELU( A[8 x R] @ B + b ), B pre-packed; M=8 on a
//   16-row MFMA (A row index clamped &7; invalid D rows never stored).
// ---------------------------------------------------------------------
template <int K, int K2, int OUTBF>
__global__ __launch_bounds__(256) void spline_layer_kernel(
    const float4* __restrict__ rec, const int* __restrict__ row_start,
    const unsigned short* __restrict__ Xbf, const unsigned short* __restrict__ Bpk,
    const float* __restrict__ bias, void* __restrict__ outv, int N) {
  constexpr int RZ = K2 * 64;
  constexpr int R = (K2 + 1) * 64;     // 640 (K=3) / 1664 (K=5)
  constexpr int AS = R + 8;            // LDS row stride (shorts)
  constexpr int NKC = R / 32;          // 20 / 52
  __shared__ unsigned short As[8 * AS];
  const int t = threadIdx.x, w = t >> 6, lane = t & 63;
  const int nodeBase = blockIdx.x * 8;

  const int col = lane & 31, half = lane >> 5;
  const int mi0 = (col < K2) ? (col % K) : -3;
  const int mi1 = (col < K2) ? (col / K) : -3;

  // ---------- phase 1: zbuild 2 nodes per wave into LDS ----------
  for (int g = 0; g < 2; ++g) {
    const int row = w * 2 + g;
    const int node = nodeBase + row;
    if (node < N) {
      floatx16 d0, d1;
#pragma unroll
      for (int i = 0; i < 16; ++i) { d0[i] = 0.f; d1[i] = 0.f; }

      const int beg = row_start[node], end = row_start[node + 1];
      for (int c0 = beg; c0 < end; c0 += 16) {
        const int m = min(16, end - c0);
        float4 rj[8];
#pragma unroll
        for (int j = 0; j < 8; ++j) {
          int idx = half * 8 + j;
          rj[j] = rec[c0 + min(idx, m - 1)];
          if (idx >= m) rj[j].z = __builtin_bit_cast(float, 0x7F7F);
        }
        short8 A, Blo, Bhi;
#pragma unroll
        for (int j = 0; j < 8; ++j) {
          int lp = __builtin_bit_cast(int, rj[j].z);
          int off = __builtin_bit_cast(int, rj[j].w);
          int l0 = lp & 0xFF, l1 = (lp >> 8) & 0xFF;
          float su = (mi0 == l0) ? (1.f - rj[j].x) : ((mi0 == l0 + 1) ? rj[j].x : 0.f);
          float sv = (mi1 == l1) ? (1.f - rj[j].y) : ((mi1 == l1 + 1) ? rj[j].y : 0.f);
          A[j] = (short)f2bf(su * sv);
          Blo[j] = (short)Xbf[off + col];
          Bhi[j] = (short)Xbf[off + 32 + col];
        }
        d0 = __builtin_amdgcn_mfma_f32_32x32x16_bf16(A, Blo, d0, 0, 0, 0);
        d1 = __builtin_amdgcn_mfma_f32_32x32x16_bf16(A, Bhi, d1, 0, 0, 0);
      }

      const float inv = 1.f / (float)max(end - beg, 1);
#pragma unroll
      for (int reg = 0; reg < 16; ++reg) {
        int r = (reg & 3) + 8 * (reg >> 2) + 4 * half;
        if (r < K2) {
          As[row * AS + r * 64 + col] = f2bf(d0[reg] * inv);
          As[row * AS + r * 64 + 32 + col] = f2bf(d1[reg] * inv);
        }
      }
      As[row * AS + RZ + lane] = Xbf[(size_t)node * 64 + lane];  // root row
    } else {
      for (int i = lane; i < R; i += 64) As[row * AS + i] = 0;
    }
  }
  __syncthreads();

  // ---------- phase 2: 8 x R x 64 GEMM + bias + ELU ----------
  const int mrow = lane & 15, q = lane >> 4;
  floatx4 acc = {0.f, 0.f, 0.f, 0.f};
  for (int kc = 0; kc < NKC; ++kc) {
    short8 a = *(const short8*)&As[(mrow & 7) * AS + kc * 32 + q * 8];
    short8 b = *(const short8*)&Bpk[(((size_t)kc * 4 + w) * 64 + lane) * 8];
    acc = __builtin_amdgcn_mfma_f32_16x16x32_bf16(a, b, acc, 0, 0, 0);
  }

  // D layout: col = lane&15 (o_local), row = q*4+reg; rows >= 8 are dupes
  const int o = w * 16 + mrow;
  const float bv = bias[o];
#pragma unroll
  for (int reg = 0; reg < 4; ++reg) {
    int row = q * 4 + reg;
    int node = nodeBase + row;
    if (row < 8 && node < N) {
      float v = acc[reg] + bv;
      v = v > 0.f ? v : (expf(v) - 1.f);
      if (OUTBF)
        ((unsigned short*)outv)[(size_t)node * 64 + o] = f2bf(v);
      else
        ((float*)outv)[(size_t)node * 64 + o] = v;
    }
  }
}

// ---------------------------------------------------------------------
// FUSED MLP head: out = relu( relu(h2 @ m1w + m1b) @ m2w + m2b )
// Block = 64 nodes. Stage h2 (bf16) -> MFMA vs pre-packed m1pk -> ReLU ->
// LDS -> 64->8 projection (VALU) -> ReLU -> out.
// ---------------------------------------------------------------------
__global__ __launch_bounds__(256) void head_kernel(
    const unsigned short* __restrict__ h2bf, const unsigned short* __restrict__ m1pk,
    const float* __restrict__ m1b, const float* __restrict__ m2w,
    const float* __restrict__ m2b, float* __restrict__ out, int N) {
  __shared__ unsigned short Hs[64 * 72];
  __shared__ unsigned short Ts[64 * 72];
  __shared__ float W2s[512];
  const int t = threadIdx.x, w = t >> 6, lane = t & 63;
  const int n0 = blockIdx.x * 64;

  for (int i = t; i < 512; i += 256) {
    int row = i >> 3, cg = i & 7;
    int n = n0 + row;
    floatx4 val = {0.f, 0.f, 0.f, 0.f};
    if (n < N) val = *(const floatx4*)&h2bf[(size_t)n * 64 + cg * 8];
    *(floatx4*)&Hs[row * 72 + cg * 8] = val;
  }
  for (int i = t; i < 512; i += 256) W2s[i] = m2w[i];
  __syncthreads();

  const int mrow = lane & 15, q = lane >> 4;
  const int o = w * 16 + mrow;
  const float bv = m1b[o];
#pragma unroll
  for (int rg = 0; rg < 4; ++rg) {
    floatx4 acc = {0.f, 0.f, 0.f, 0.f};
#pragma unroll
    for (int kc = 0; kc < 2; ++kc) {
      short8 a = *(const short8*)&Hs[(rg * 16 + mrow) * 72 + kc * 32 + q * 8];
      short8 b = *(const short8*)&m1pk[(((size_t)kc * 4 + w) * 64 + lane) * 8];
      acc = __builtin_amdgcn_mfma_f32_16x16x32_bf16(a, b, acc, 0, 0, 0);
    }
#pragma unroll
    for (int reg = 0; reg < 4; ++reg) {
      int row = rg * 16 + q * 4 + reg;
      float v = acc[reg] + bv;
      Ts[row * 72 + o] = f2bf(v > 0.f ? v : 0.f);
    }
  }
  __syncthreads();

  // 64 -> 8 projection with ReLU
  for (int i = t; i < 512; i += 256) {
    int nl = i >> 3, c = i & 7;
    int n = n0 + nl;
    if (n >= N) continue;
    float s = m2b[c];
    for (int d = 0; d < 64; ++d) s += bf2f(Ts[nl * 72 + d]) * W2s[d * 8 + c];
    out[(size_t)n * 8 + c] = s > 0.f ? s : 0.f;
  }
}

// ---------------------------------------------------------------------
extern "C" void kernel_launch(void* const* d_in, const int* in_sizes, int n_in,
                              void* d_out, int out_size, void* d_ws, size_t ws_size,
                              hipStream_t stream) {
  const float* x     = (const float*)d_in[0];
  const int*   ei    = (const int*)d_in[1];
  const float* attr  = (const float*)d_in[2];
  const float* W1    = (const float*)d_in[3];
  const float* root1 = (const float*)d_in[4];
  const float* b1    = (const float*)d_in[5];
  const float* W2    = (const float*)d_in[6];
  const float* root2 = (const float*)d_in[7];
  const float* b2    = (const float*)d_in[8];
  const float* m1w   = (const float*)d_in[9];
  const float* m1b   = (const float*)d_in[10];
  const float* m2w   = (const float*)d_in[11];
  const float* m2b   = (const float*)d_in[12];

  const int N  = in_sizes[0] / 64;
  const int nE = in_sizes[1] / 2;
  const int* src  = ei;
  const int* dstv = ei + nE;
  float* out = (float*)d_out;

  // workspace layout
  int* deg       = (int*)d_ws;
  int* row_start = deg + N;
  int* cursor    = row_start + (N + 1);
  int* partial   = cursor + N;              // 256
  char* pbase = (char*)(partial + 256);
  pbase = (char*)(((uintptr_t)pbase + 15) & ~(uintptr_t)15);
  float4* rec3 = (float4*)pbase;                        // nE * 16B
  float4* rec5 = rec3 + nE;                             // nE * 16B
  unsigned short* Xbf  = (unsigned short*)(rec5 + nE);  // N*64 bf16
  unsigned short* h1bf = Xbf + (size_t)N * 64;          // N*64 bf16
  unsigned short* h2bf = h1bf + (size_t)N * 64;         // N*64 bf16
  unsigned short* Bpk1 = h2bf + (size_t)N * 64;         // 64 * 640
  unsigned short* Bpk2 = Bpk1 + 64 * 640;               // 64 * 1664
  unsigned short* m1pk = Bpk2 + 64 * 1664;              // 64 * 64

  dim3 blk(256);
  int nbN  = (N + 255) / 256;
  int nbE  = (nE + 255) / 256;
  int nbF  = (N + 7) / 8;
  int nbH  = (N + 63) / 64;

  // ----- CSR build (graph identical both layers) -----
  zero_int_kernel<<<nbN, blk, 0, stream>>>(deg, N);
  hist_kernel<<<nbE, blk, 0, stream>>>(dstv, deg, nE);
  blocksum_kernel<<<nbN, blk, 0, stream>>>(deg, partial, N);
  scanpartials_kernel<<<1, blk, 0, stream>>>(partial, nbN);
  blockscan_kernel<<<nbN, blk, 0, stream>>>(deg, partial, row_start, cursor, N, nE);
  scatter_rec_kernel<<<nbE, blk, 0, stream>>>(dstv, src, attr, cursor, rec3, rec5, nE);

  // ----- weight / input prep -----
  pack_b_kernel<<<(64 * 640 + 255) / 256, blk, 0, stream>>>(W1, root1, Bpk1, 9);
  pack_b_kernel<<<(64 * 1664 + 255) / 256, blk, 0, stream>>>(W2, root2, Bpk2, 25);
  pack_b_kernel<<<(64 * 64 + 255) / 256, blk, 0, stream>>>(m1w, m1w, m1pk, 0);
  cvt_x_kernel<<<(N * 64 + 255) / 256, blk, 0, stream>>>(x, Xbf, N * 64);

  // ----- layer 1 (K=3, K2=9): fused zbuild+GEMM, bf16 out -----
  spline_layer_kernel<3, 9, 1><<<nbF, blk, 0, stream>>>(
      rec3, row_start, Xbf, Bpk1, b1, h1bf, N);

  // ----- layer 2 (K=5, K2=25): fused zbuild+GEMM, bf16 out -----
  spline_layer_kernel<5, 25, 1><<<nbF, blk, 0, stream>>>(
      rec5, row_start, h1bf, Bpk2, b2, h2bf, N);

  // ----- fused MLP head -----
  head_kernel<<<nbH, blk, 0, stream>>>(h2bf, m1pk, m1b, m2w, m2b, out, N);
}

// Round 16
// 345.536 us; speedup vs baseline: 1.0888x; 1.0888x over previous
//
#include <hip/hip_runtime.h>
#include <hip/hip_bf16.h>

typedef __attribute__((ext_vector_type(8))) short short8;
typedef __attribute__((ext_vector_type(4))) float floatx4;
typedef __attribute__((ext_vector_type(16))) float floatx16;

__device__ __forceinline__ unsigned short f2bf(float x) {
  __hip_bfloat16 h = __float2bfloat16(x);
  return __builtin_bit_cast(unsigned short, h);
}
__device__ __forceinline__ float bf2f(unsigned short u) {
  return __builtin_bit_cast(float, (unsigned int)u << 16);
}

// ---------------------------------------------------------------------
// X (fp32) -> bf16 copy
// ---------------------------------------------------------------------
__global__ __launch_bounds__(256) void cvt_x_kernel(
    const float* __restrict__ X, unsigned short* __restrict__ Xbf, int n) {
  int i = blockIdx.x * 256 + threadIdx.x;
  if (i < n) Xbf[i] = f2bf(X[i]);
}

// ---------------------------------------------------------------------
// Pack extended weights [W | root] into MFMA B-fragment order:
// Bpk[(((kc*4)+wv)*64 + lane)*8 + j] = Wext[wv*16 + (lane&15)]
//                                          [kc*32 + ((lane>>4)&3)*8 + j]
// K2=0 packs just a 64x64 matrix from `root`.
// ---------------------------------------------------------------------
__global__ __launch_bounds__(256) void pack_b_kernel(
    const float* __restrict__ W, const float* __restrict__ root,
    unsigned short* __restrict__ Bpk, int K2) {
  int R = (K2 + 1) * 64;
  int total = 64 * R;
  int i = blockIdx.x * 256 + threadIdx.x;
  if (i >= total) return;
  int j = i & 7;
  int lane = (i >> 3) & 63;
  int rest = i >> 9;            // kc*4 + wv
  int wv = rest & 3, kc = rest >> 2;
  int o = wv * 16 + (lane & 15);
  int r = kc * 32 + ((lane >> 4) & 3) * 8 + j;
  int k = r >> 6, d = r & 63;
  float v = (k < K2) ? W[(k << 12) + (d << 6) + o] : root[(d << 6) + o];
  Bpk[i] = f2bf(v);
}

// ---------------------------------------------------------------------
// CSR build: histogram -> scan -> cursor scatter (emits packed edge recs)
// ---------------------------------------------------------------------
__global__ __launch_bounds__(256) void zero_int_kernel(int* __restrict__ p, int n) {
  int i = blockIdx.x * 256 + threadIdx.x;
  if (i < n) p[i] = 0;
}

__global__ __launch_bounds__(256) void hist_kernel(
    const int* __restrict__ dst, int* __restrict__ deg, int nE) {
  int e = blockIdx.x * 256 + threadIdx.x;
  if (e < nE) atomicAdd(&deg[dst[e]], 1);
}

__global__ __launch_bounds__(256) void blocksum_kernel(
    const int* __restrict__ deg, int* __restrict__ partial, int N) {
  __shared__ int s[256];
  int t = threadIdx.x, i = blockIdx.x * 256 + t;
  s[t] = (i < N) ? deg[i] : 0;
  __syncthreads();
  for (int off = 128; off > 0; off >>= 1) {
    if (t < off) s[t] += s[t + off];
    __syncthreads();
  }
  if (t == 0) partial[blockIdx.x] = s[0];
}

__global__ __launch_bounds__(256) void scanpartials_kernel(
    int* __restrict__ partial, int nb) {
  __shared__ int s[256];
  int t = threadIdx.x;
  int v = (t < nb) ? partial[t] : 0;
  s[t] = v;
  __syncthreads();
  for (int off = 1; off < 256; off <<= 1) {
    int x = (t >= off) ? s[t - off] : 0;
    __syncthreads();
    s[t] += x;
    __syncthreads();
  }
  if (t < nb) partial[t] = s[t] - v;
}

__global__ __launch_bounds__(256) void blockscan_kernel(
    const int* __restrict__ deg, const int* __restrict__ partial,
    int* __restrict__ row_start, int* __restrict__ cursor, int N, int nE) {
  __shared__ int s[256];
  int t = threadIdx.x, i = blockIdx.x * 256 + t;
  int v = (i < N) ? deg[i] : 0;
  s[t] = v;
  __syncthreads();
  for (int off = 1; off < 256; off <<= 1) {
    int x = (t >= off) ? s[t - off] : 0;
    __syncthreads();
    s[t] += x;
    __syncthreads();
  }
  if (i < N) {
    int excl = s[t] - v + partial[blockIdx.x];
    row_start[i] = excl;
    cursor[i] = excl;
  }
  if (i == 0) row_start[N] = nE;
}

// Record: x=f0, y=f1, z=bit(l0|l1<<8), w=bit(src*64). One per edge per K.
__global__ __launch_bounds__(256) void scatter_rec_kernel(
    const int* __restrict__ dst, const int* __restrict__ src,
    const float* __restrict__ attr, int* __restrict__ cursor,
    float4* __restrict__ rec3, float4* __restrict__ rec5, int nE) {
  int e = blockIdx.x * 256 + threadIdx.x;
  if (e >= nE) return;
  int pos = atomicAdd(&cursor[dst[e]], 1);
  float2 a = *(const float2*)&attr[2 * e];
  int off = src[e] * 64;
  {
    float u = a.x * 2.f, v = a.y * 2.f;
    int l0 = min((int)u, 1), l1 = min((int)v, 1);
    rec3[pos] = make_float4(u - (float)l0, v - (float)l1,
                            __builtin_bit_cast(float, l0 | (l1 << 8)),
                            __builtin_bit_cast(float, off));
  }
  {
    float u = a.x * 4.f, v = a.y * 4.f;
    int l0 = min((int)u, 3), l1 = min((int)v, 3);
    rec5[pos] = make_float4(u - (float)l0, v - (float)l1,
                            __builtin_bit_cast(float, l0 | (l1 << 8)),
                            __builtin_bit_cast(float, off));
  }
}

// ---------------------------------------------------------------------
// FUSED spline layer: block = 4 waves = 16 dst nodes (4 nodes/wave).
// Phase 1 (per wave): MFMA bucket-aggregate (32x32x16) from packed edge
//   records; scaled Z (buckets only) -> LDS.  Root row is NOT stored:
//   phase 2 reads it straight from the layer input (coalesced 16B/lane),
//   trimming LDS to 51.5 KB -> 3 blocks/CU (R13's 54.8 KB allowed only 2).
// Phase 2: out[16 x 64] = ELU( [Az | X] @ B + b ), B pre-packed.
// ---------------------------------------------------------------------
template <int K, int K2, int OUTBF>
__global__ __launch_bounds__(256) void spline_layer_kernel(
    const float4* __restrict__ rec, const int* __restrict__ row_start,
    const unsigned short* __restrict__ Xbf, const unsigned short* __restrict__ Bpk,
    const float* __restrict__ bias, void* __restrict__ outv, int N) {
  constexpr int RZ = K2 * 64;          // bucket columns: 576 / 1600
  constexpr int AS = RZ + 8;           // LDS row stride (shorts, 16B-mult)
  constexpr int NKZ = RZ / 32;         // 18 / 50
  constexpr int NKC = (K2 + 1) * 2;    // 20 / 52
  __shared__ unsigned short As[16 * AS];
  const int t = threadIdx.x, w = t >> 6, lane = t & 63;
  const int nodeBase = blockIdx.x * 16;

  const int col = lane & 31, half = lane >> 5;
  const int mi0 = (col < K2) ? (col % K) : -3;
  const int mi1 = (col < K2) ? (col / K) : -3;

  // ---------- phase 1: zbuild 4 nodes per wave into LDS ----------
  for (int g = 0; g < 4; ++g) {
    const int row = w * 4 + g;
    const int node = nodeBase + row;
    if (node < N) {
      floatx16 d0, d1;
#pragma unroll
      for (int i = 0; i < 16; ++i) { d0[i] = 0.f; d1[i] = 0.f; }

      const int beg = row_start[node], end = row_start[node + 1];
      for (int c0 = beg; c0 < end; c0 += 16) {
        const int m = min(16, end - c0);
        float4 rj[8];
#pragma unroll
        for (int j = 0; j < 8; ++j) {
          int idx = half * 8 + j;
          rj[j] = rec[c0 + min(idx, m - 1)];
          if (idx >= m) rj[j].z = __builtin_bit_cast(float, 0x7F7F);
        }
        short8 A, Blo, Bhi;
#pragma unroll
        for (int j = 0; j < 8; ++j) {
          int lp = __builtin_bit_cast(int, rj[j].z);
          int off = __builtin_bit_cast(int, rj[j].w);
          int l0 = lp & 0xFF, l1 = (lp >> 8) & 0xFF;
          float su = (mi0 == l0) ? (1.f - rj[j].x) : ((mi0 == l0 + 1) ? rj[j].x : 0.f);
          float sv = (mi1 == l1) ? (1.f - rj[j].y) : ((mi1 == l1 + 1) ? rj[j].y : 0.f);
          A[j] = (short)f2bf(su * sv);
          Blo[j] = (short)Xbf[off + col];
          Bhi[j] = (short)Xbf[off + 32 + col];
        }
        d0 = __builtin_amdgcn_mfma_f32_32x32x16_bf16(A, Blo, d0, 0, 0, 0);
        d1 = __builtin_amdgcn_mfma_f32_32x32x16_bf16(A, Bhi, d1, 0, 0, 0);
      }

      const float inv = 1.f / (float)max(end - beg, 1);
#pragma unroll
      for (int reg = 0; reg < 16; ++reg) {
        int r = (reg & 3) + 8 * (reg >> 2) + 4 * half;
        if (r < K2) {
          As[row * AS + r * 64 + col] = f2bf(d0[reg] * inv);
          As[row * AS + r * 64 + 32 + col] = f2bf(d1[reg] * inv);
        }
      }
    } else {
      for (int i = lane; i < RZ; i += 64) As[row * AS + i] = 0;
    }
  }
  __syncthreads();

  // ---------- phase 2: 16 x R x 64 GEMM + bias + ELU ----------
  const int mrow = lane & 15, q = lane >> 4;
  const int anode = min(nodeBase + mrow, N - 1);  // root-row source (clamped;
                                                  // garbage only hits discarded rows)
  floatx4 acc = {0.f, 0.f, 0.f, 0.f};
#pragma unroll
  for (int kc = 0; kc < NKC; ++kc) {
    short8 a;
    if (kc < NKZ)
      a = *(const short8*)&As[mrow * AS + kc * 32 + q * 8];
    else
      a = *(const short8*)&Xbf[(size_t)anode * 64 + (kc - NKZ) * 32 + q * 8];
    short8 b = *(const short8*)&Bpk[(((size_t)kc * 4 + w) * 64 + lane) * 8];
    acc = __builtin_amdgcn_mfma_f32_16x16x32_bf16(a, b, acc, 0, 0, 0);
  }

  // D layout: col = lane&15 -> o_local, row = q*4+reg -> node_local
  const int o = w * 16 + mrow;
  const float bv = bias[o];
#pragma unroll
  for (int reg = 0; reg < 4; ++reg) {
    int node = nodeBase + q * 4 + reg;
    if (node < N) {
      float v = acc[reg] + bv;
      v = v > 0.f ? v : (expf(v) - 1.f);
      if (OUTBF)
        ((unsigned short*)outv)[(size_t)node * 64 + o] = f2bf(v);
      else
        ((float*)outv)[(size_t)node * 64 + o] = v;
    }
  }
}

// ---------------------------------------------------------------------
// FUSED MLP head: out = relu( relu(h2 @ m1w + m1b) @ m2w + m2b )
// ---------------------------------------------------------------------
__global__ __launch_bounds__(256) void head_kernel(
    const unsigned short* __restrict__ h2bf, const unsigned short* __restrict__ m1pk,
    const float* __restrict__ m1b, const float* __restrict__ m2w,
    const float* __restrict__ m2b, float* __restrict__ out, int N) {
  __shared__ unsigned short Hs[64 * 72];
  __shared__ unsigned short Ts[64 * 72];
  __shared__ float W2s[512];
  const int t = threadIdx.x, w = t >> 6, lane = t & 63;
  const int n0 = blockIdx.x * 64;

  for (int i = t; i < 512; i += 256) {
    int row = i >> 3, cg = i & 7;
    int n = n0 + row;
    floatx4 val = {0.f, 0.f, 0.f, 0.f};
    if (n < N) val = *(const floatx4*)&h2bf[(size_t)n * 64 + cg * 8];
    *(floatx4*)&Hs[row * 72 + cg * 8] = val;
  }
  for (int i = t; i < 512; i += 256) W2s[i] = m2w[i];
  __syncthreads();

  const int mrow = lane & 15, q = lane >> 4;
  const int o = w * 16 + mrow;
  const float bv = m1b[o];
#pragma unroll
  for (int rg = 0; rg < 4; ++rg) {
    floatx4 acc = {0.f, 0.f, 0.f, 0.f};
#pragma unroll
    for (int kc = 0; kc < 2; ++kc) {
      short8 a = *(const short8*)&Hs[(rg * 16 + mrow) * 72 + kc * 32 + q * 8];
      short8 b = *(const short8*)&m1pk[(((size_t)kc * 4 + w) * 64 + lane) * 8];
      acc = __builtin_amdgcn_mfma_f32_16x16x32_bf16(a, b, acc, 0, 0, 0);
    }
#pragma unroll
    for (int reg = 0; reg < 4; ++reg) {
      int row = rg * 16 + q * 4 + reg;
      float v = acc[reg] + bv;
      Ts[row * 72 + o] = f2bf(v > 0.f ? v : 0.f);
    }
  }
  __syncthreads();

  // 64 -> 8 projection with ReLU
  for (int i = t; i < 512; i += 256) {
    int nl = i >> 3, c = i & 7;
    int n = n0 + nl;
    if (n >= N) continue;
    float s = m2b[c];
    for (int d = 0; d < 64; ++d) s += bf2f(Ts[nl * 72 + d]) * W2s[d * 8 + c];
    out[(size_t)n * 8 + c] = s > 0.f ? s : 0.f;
  }
}

// ---------------------------------------------------------------------
extern "C" void kernel_launch(void* const* d_in, const int* in_sizes, int n_in,
                              void* d_out, int out_size, void* d_ws, size_t ws_size,
                              hipStream_t stream) {
  const float* x     = (const float*)d_in[0];
  const int*   ei    = (const int*)d_in[1];
  const float* attr  = (const float*)d_in[2];
  const float* W1    = (const float*)d_in[3];
  const float* root1 = (const float*)d_in[4];
  const float* b1    = (const float*)d_in[5];
  const float* W2    = (const float*)d_in[6];
  const float* root2 = (const float*)d_in[7];
  const float* b2    = (const float*)d_in[8];
  const float* m1w   = (const float*)d_in[9];
  const float* m1b   = (const float*)d_in[10];
  const float* m2w   = (const float*)d_in[11];
  const float* m2b   = (const float*)d_in[12];

  const int N  = in_sizes[0] / 64;
  const int nE = in_sizes[1] / 2;
  const int* src  = ei;
  const int* dstv = ei + nE;
  float* out = (float*)d_out;

  // workspace layout
  int* deg       = (int*)d_ws;
  int* row_start = deg + N;
  int* cursor    = row_start + (N + 1);
  int* partial   = cursor + N;              // 256
  char* pbase = (char*)(partial + 256);
  pbase = (char*)(((uintptr_t)pbase + 15) & ~(uintptr_t)15);
  float4* rec3 = (float4*)pbase;                        // nE * 16B
  float4* rec5 = rec3 + nE;                             // nE * 16B
  unsigned short* Xbf  = (unsigned short*)(rec5 + nE);  // N*64 bf16
  unsigned short* h1bf = Xbf + (size_t)N * 64;          // N*64 bf16
  unsigned short* h2bf = h1bf + (size_t)N * 64;         // N*64 bf16
  unsigned short* Bpk1 = h2bf + (size_t)N * 64;         // 64 * 640
  unsigned short* Bpk2 = Bpk1 + 64 * 640;               // 64 * 1664
  unsigned short* m1pk = Bpk2 + 64 * 1664;              // 64 * 64

  dim3 blk(256);
  int nbN  = (N + 255) / 256;
  int nbE  = (nE + 255) / 256;
  int nbF  = (N + 15) / 16;
  int nbH  = (N + 63) / 64;

  // ----- CSR build (graph identical both layers) -----
  zero_int_kernel<<<nbN, blk, 0, stream>>>(deg, N);
  hist_kernel<<<nbE, blk, 0, stream>>>(dstv, deg, nE);
  blocksum_kernel<<<nbN, blk, 0, stream>>>(deg, partial, N);
  scanpartials_kernel<<<1, blk, 0, stream>>>(partial, nbN);
  blockscan_kernel<<<nbN, blk, 0, stream>>>(deg, partial, row_start, cursor, N, nE);
  scatter_rec_kernel<<<nbE, blk, 0, stream>>>(dstv, src, attr, cursor, rec3, rec5, nE);

  // ----- weight / input prep -----
  pack_b_kernel<<<(64 * 640 + 255) / 256, blk, 0, stream>>>(W1, root1, Bpk1, 9);
  pack_b_kernel<<<(64 * 1664 + 255) / 256, blk, 0, stream>>>(W2, root2, Bpk2, 25);
  pack_b_kernel<<<(64 * 64 + 255) / 256, blk, 0, stream>>>(m1w, m1w, m1pk, 0);
  cvt_x_kernel<<<(N * 64 + 255) / 256, blk, 0, stream>>>(x, Xbf, N * 64);

  // ----- layer 1 (K=3, K2=9): fused zbuild+GEMM, bf16 out -----
  spline_layer_kernel<3, 9, 1><<<nbF, blk, 0, stream>>>(
      rec3, row_start, Xbf, Bpk1, b1, h1bf, N);

  // ----- layer 2 (K=5, K2=25): fused zbuild+GEMM, bf16 out -----
  spline_layer_kernel<5, 25, 1><<<nbF, blk, 0, stream>>>(
      rec5, row_start, h1bf, Bpk2, b2, h2bf, N);

  // ----- fused MLP head -----
  head_kernel<<<nbH, blk, 0, stream>>>(h2bf, m1pk, m1b, m2w, m2b, out, N);
}